// Round 16
// baseline (256.924 us; speedup 1.0000x reference)
//
#include <hip/hip_runtime.h>

typedef unsigned short u16;
typedef __attribute__((ext_vector_type(8))) short short8;
typedef __attribute__((ext_vector_type(4))) float f32x4;

// ws float-index offsets
#define OFF_U     0       // [4][4][64] folded value vectors (tag,h,k)
#define OFF_CV    1024    // [4][4]
#define OFF_CONST 1040
#define OFF_CTAG  1044    // [4] per-tag bo.wfh sums
#define OFF_BA    1056    // [272] fp32 bias for WA cols
#define OFF_BB    1328    // [272]
// ws byte offsets (16B-aligned)
#define OFF_WA_B    6400     // u16 [17][2][64][8]  WA frag-ordered
#define OFF_WB_B    41216    // u16 [17][2][64][8]  WB frag-ordered
#define OFF_W2P_B   76032    // u16 [8][32][64][8]  w2 in frag order
#define OFF_W3P_B   338176   // u16 [8][16][64][8]  w3 in frag order
#define OFF_TOK_B   469248   // u16 tokens, D-MAJOR: [8][65536][64]

#define P_STRIDE 280
#define PSIDE    (32 * P_STRIDE)

static __device__ __forceinline__ u16 f2bf(float f) {
  unsigned int bits = __float_as_uint(f);
  bits += 0x7fffu + ((bits >> 16) & 1u);
  return (u16)(bits >> 16);
}
static __device__ __forceinline__ float bf2f(u16 u) {
  return __uint_as_float(((unsigned int)u) << 16);
}
static __device__ __forceinline__ void ld16(const u16* p, float* o) {
  short8 v0 = *(const short8*)p;
  short8 v1 = *(const short8*)(p + 8);
#pragma unroll
  for (int i = 0; i < 8; i++) {
    o[i] = bf2f((u16)v0[i]);
    o[8 + i] = bf2f((u16)v1[i]);
  }
}

// ---------------------------------------------------------------- prep 1: fold
__global__ __launch_bounds__(64) void prep_fold(
    const float* __restrict__ win_sa, const float* __restrict__ bin_sa,
    const float* __restrict__ wo_sa,  const float* __restrict__ bo_sa,
    const float* __restrict__ win_sb, const float* __restrict__ bin_sb,
    const float* __restrict__ wo_sb,  const float* __restrict__ bo_sb,
    const float* __restrict__ win_ca, const float* __restrict__ bin_ca,
    const float* __restrict__ wo_ca,  const float* __restrict__ bo_ca,
    const float* __restrict__ win_cb, const float* __restrict__ bin_cb,
    const float* __restrict__ wo_cb,  const float* __restrict__ bo_cb,
    const float* __restrict__ Wf, float* __restrict__ ws) {
  __shared__ float v_lds[64];
  const int t = threadIdx.x;
  const int tag = blockIdx.x;
  const float* wins[4] = {win_sa, win_sb, win_ca, win_cb};
  const float* bins[4] = {bin_sa, bin_sb, bin_ca, bin_cb};
  const float* wos[4]  = {wo_sa, wo_sb, wo_ca, wo_cb};
  const float* bos[4]  = {bo_sa, bo_sb, bo_ca, bo_cb};
  const float* wfh = Wf + ((tag == 0 || tag == 2) ? 0 : 64);
  float v = 0.f;
#pragma unroll
  for (int e = 0; e < 64; e++) v += wos[tag][e * 64 + t] * wfh[e];
  v_lds[t] = v;
  __syncthreads();
#pragma unroll
  for (int h = 0; h < 4; h++) {
    float u = 0.f;
#pragma unroll
    for (int dp = 0; dp < 16; dp++)
      u += wins[tag][(128 + h * 16 + dp) * 64 + t] * v_lds[h * 16 + dp];
    ws[OFF_U + tag * 256 + h * 64 + t] = u;
  }
  if (t < 4) {
    float cv = 0.f;
#pragma unroll
    for (int dp = 0; dp < 16; dp++)
      cv += bins[tag][128 + t * 16 + dp] * v_lds[t * 16 + dp];
    ws[OFF_CV + tag * 4 + t] = cv;
  }
  if (t == 0) {
    float c = 0.f;
#pragma unroll
    for (int e = 0; e < 64; e++) c += bos[tag][e] * wfh[e];
    ws[OFF_CTAG + tag] = c;
  }
}

// ---------------------------------------------------------------- prep 2: pack
__global__ __launch_bounds__(256) void prep_pack(
    const float* __restrict__ w2, const float* __restrict__ w3,
    const float* __restrict__ win_sa, const float* __restrict__ win_sb,
    const float* __restrict__ win_ca, const float* __restrict__ win_cb,
    const float* __restrict__ bin_sa, const float* __restrict__ bin_sb,
    const float* __restrict__ bin_ca, const float* __restrict__ bin_cb,
    const float* __restrict__ bf,
    float* __restrict__ ws, u16* __restrict__ w2p, u16* __restrict__ w3p,
    u16* __restrict__ WA, u16* __restrict__ WB) {
  int idx = blockIdx.x * 256 + threadIdx.x;
  if (idx < 131072) {               // w2p[d][ks*8+nt][lane][j]
    int d = idx >> 14, rem = idx & 16383;
    int f = rem >> 9, ks = f >> 3, nt = f & 7;
    int r2 = rem & 511, l = r2 >> 3, j = r2 & 7;
    int quad = l >> 4, m15 = l & 15;
    w2p[idx] = f2bf(w2[(d * 128 + nt * 16 + m15) * 128 + ks * 32 + quad * 8 + j]);
  } else if (idx < 196608) {        // w3p[d][ks*4+nt][lane][j]
    int i = idx - 131072;
    int d = i >> 13, rem = i & 8191;
    int f = rem >> 9, ks = f >> 2, nt = f & 3;
    int r2 = rem & 511, l = r2 >> 3, j = r2 & 7;
    int quad = l >> 4, m15 = l & 15;
    w3p[i] = f2bf(w3[(d * 64 + nt * 16 + m15) * 128 + ks * 32 + quad * 8 + j]);
  } else if (idx < 214016) {        // WAf [17][2][64][8]
    int i = idx - 196608;
    int nt = i >> 10, rem = i & 1023;
    int half = rem >> 9, r2 = rem & 511, l = r2 >> 3, j = r2 & 7;
    int n = nt * 16 + (l & 15), k = half * 32 + (l >> 4) * 8 + j;
    float v;
    if (n < 64)       v = win_sa[n * 64 + k] * 0.25f;
    else if (n < 128) v = win_sa[n * 64 + k];
    else if (n < 192) v = win_ca[(n - 128) * 64 + k] * 0.25f;
    else if (n < 256) v = win_cb[(n - 128) * 64 + k];
    else if (n < 260) v = ws[OFF_U + 0 * 256 + (n - 256) * 64 + k];
    else if (n < 264) v = ws[OFF_U + 3 * 256 + (n - 260) * 64 + k];
    else              v = 0.f;
    WA[i] = f2bf(v);
  } else if (idx < 231424) {        // WBf [17][2][64][8]
    int i = idx - 214016;
    int nt = i >> 10, rem = i & 1023;
    int half = rem >> 9, r2 = rem & 511, l = r2 >> 3, j = r2 & 7;
    int n = nt * 16 + (l & 15), k = half * 32 + (l >> 4) * 8 + j;
    float v;
    if (n < 64)       v = win_sb[n * 64 + k] * 0.25f;
    else if (n < 128) v = win_sb[n * 64 + k];
    else if (n < 192) v = win_cb[(n - 128) * 64 + k] * 0.25f;
    else if (n < 256) v = win_ca[(n - 128) * 64 + k];
    else if (n < 260) v = ws[OFF_U + 1 * 256 + (n - 256) * 64 + k];
    else if (n < 264) v = ws[OFF_U + 2 * 256 + (n - 260) * 64 + k];
    else              v = 0.f;
    WB[i] = f2bf(v);
  } else if (idx < 231696) {        // bA
    int n = idx - 231424;
    float v;
    if (n < 64)       v = bin_sa[n] * 0.25f;
    else if (n < 128) v = bin_sa[n];
    else if (n < 192) v = bin_ca[n - 128] * 0.25f;
    else if (n < 256) v = bin_cb[n - 128];
    else if (n < 260) v = ws[OFF_CV + 0 * 4 + (n - 256)];
    else if (n < 264) v = ws[OFF_CV + 3 * 4 + (n - 260)];
    else              v = 0.f;
    ws[OFF_BA + n] = v;
  } else if (idx < 231968) {        // bB
    int n = idx - 231696;
    float v;
    if (n < 64)       v = bin_sb[n] * 0.25f;
    else if (n < 128) v = bin_sb[n];
    else if (n < 192) v = bin_cb[n - 128] * 0.25f;
    else if (n < 256) v = bin_ca[n - 128];
    else if (n < 260) v = ws[OFF_CV + 1 * 4 + (n - 256)];
    else if (n < 264) v = ws[OFF_CV + 2 * 4 + (n - 260)];
    else              v = 0.f;
    ws[OFF_BB + n] = v;
  } else if (idx == 231968) {
    ws[OFF_CONST] = 0.5f * (ws[OFF_CTAG] + ws[OFF_CTAG + 1] +
                            ws[OFF_CTAG + 2] + ws[OFF_CTAG + 3]) + bf[0];
  }
}

// ---------------------------------------------------------------- tokens (MFMA)
// R15 version (best measured 78.4 us): 2 straight-line tiles per wave.
__global__ __launch_bounds__(256, 2) void tokens_kernel(
    const float* __restrict__ x, const float* __restrict__ w1,
    const float* __restrict__ b1, const float* __restrict__ b2,
    const float* __restrict__ b3, const u16* __restrict__ w2p,
    const u16* __restrict__ w3p, u16* __restrict__ tok_out) {
  __shared__ __align__(16) u16 w2l[16384];
  __shared__ __align__(16) u16 w3l[8192];
  __shared__ __align__(16) u16 h2s[4][16 * 136];
  __shared__ __align__(16) u16 stg[4][16 * 72];
  const int t = threadIdx.x;
  const int wave = t >> 6, lane = t & 63;
  const int m15 = lane & 15, quad = lane >> 4;
  const int d = blockIdx.x & 7;
  const int g = blockIdx.x >> 3;
  const int base = g * 128 + wave * 16;   // tile0; tile1 = base + 64
  const float xv0 = x[(size_t)(base + m15) * 8 + d];
  const float xv1 = x[(size_t)(base + 64 + m15) * 8 + d];
#pragma unroll
  for (int c = 0; c < 8; c++)
    *(short8*)&w2l[c * 2048 + t * 8] = *(const short8*)&w2p[d * 16384 + c * 2048 + t * 8];
#pragma unroll
  for (int c = 0; c < 4; c++)
    *(short8*)&w3l[c * 2048 + t * 8] = *(const short8*)&w3p[d * 8192 + c * 2048 + t * 8];
  __syncthreads();

  auto process_tile = [&](int b0, float xv) {
    short8 afr[4];
#pragma unroll
    for (int ks = 0; ks < 4; ks++) {
      const float* w1p = w1 + d * 128 + ks * 32 + quad * 8;
      const float* b1p = b1 + d * 128 + ks * 32 + quad * 8;
      float4 wa = *(const float4*)w1p, wb = *(const float4*)(w1p + 4);
      float4 ba = *(const float4*)b1p, bb = *(const float4*)(b1p + 4);
      short8 a;
      a[0] = (short)f2bf(__sinf(xv * wa.x + ba.x));
      a[1] = (short)f2bf(__sinf(xv * wa.y + ba.y));
      a[2] = (short)f2bf(__sinf(xv * wa.z + ba.z));
      a[3] = (short)f2bf(__sinf(xv * wa.w + ba.w));
      a[4] = (short)f2bf(__sinf(xv * wb.x + bb.x));
      a[5] = (short)f2bf(__sinf(xv * wb.y + bb.y));
      a[6] = (short)f2bf(__sinf(xv * wb.z + bb.z));
      a[7] = (short)f2bf(__sinf(xv * wb.w + bb.w));
      afr[ks] = a;
    }
    f32x4 acc2[8];
#pragma unroll
    for (int nt = 0; nt < 8; nt++) acc2[nt] = (f32x4){0.f, 0.f, 0.f, 0.f};
#pragma unroll
    for (int ks = 0; ks < 4; ks++) {
#pragma unroll
      for (int nt = 0; nt < 8; nt++) {
        short8 bfr = *(const short8*)&w2l[(ks * 8 + nt) * 512 + lane * 8];
        acc2[nt] = __builtin_amdgcn_mfma_f32_16x16x32_bf16(afr[ks], bfr, acc2[nt], 0, 0, 0);
      }
    }
#pragma unroll
    for (int nt = 0; nt < 8; nt++) {
      float bias = b2[d * 128 + m15 + 16 * nt];
#pragma unroll
      for (int r = 0; r < 4; r++)
        h2s[wave][(quad * 4 + r) * 136 + m15 + 16 * nt] =
            f2bf(__sinf(acc2[nt][r] + bias));
    }
    f32x4 acc3[4];
#pragma unroll
    for (int nt = 0; nt < 4; nt++) acc3[nt] = (f32x4){0.f, 0.f, 0.f, 0.f};
#pragma unroll
    for (int ks = 0; ks < 4; ks++) {
      short8 af = *(const short8*)(&h2s[wave][m15 * 136 + ks * 32 + quad * 8]);
#pragma unroll
      for (int nt = 0; nt < 4; nt++) {
        short8 bfr = *(const short8*)&w3l[(ks * 4 + nt) * 512 + lane * 8];
        acc3[nt] = __builtin_amdgcn_mfma_f32_16x16x32_bf16(af, bfr, acc3[nt], 0, 0, 0);
      }
    }
#pragma unroll
    for (int nt = 0; nt < 4; nt++) {
      float bias = b3[d * 64 + m15 + 16 * nt];
#pragma unroll
      for (int r = 0; r < 4; r++)
        stg[wave][(quad * 4 + r) * 72 + m15 + 16 * nt] = f2bf(acc3[nt][r] + bias);
    }
    {
      int chunk = lane & 7;
#pragma unroll
      for (int it = 0; it < 2; it++) {
        int row_l = (lane >> 3) + it * 8;
        short8 v = *(const short8*)&stg[wave][row_l * 72 + chunk * 8];
        *(short8*)(tok_out + ((size_t)(d * 65536 + b0 + row_l)) * 64 + chunk * 8) = v;
      }
    }
  };
  process_tile(base, xv0);
  process_tile(base + 64, xv1);
}

// ---------------------------------------------------------------- attention
// 16 els/block (grid 4096), double-buffered P (70 KB, 2 blocks/CU = same
// 8 waves/CU): each W frag loaded ONCE serves both element groups (2x W
// reuse vs R14). One barrier; stage B runs both groups from separate P.
__global__ __launch_bounds__(128, 2) void attn_kernel(
    const float* __restrict__ ws, const u16* __restrict__ tok,
    const u16* __restrict__ WA, const u16* __restrict__ WB,
    float* __restrict__ out) {
  __shared__ __align__(16) u16 P[2][2 * PSIDE];   // 70 KB
  const int t = threadIdx.x;
  const int wave = t >> 6, lane = t & 63;
  const int m15 = lane & 15, quad = lane >> 4;
  const int side = wave;
  const int b0 = blockIdx.x * 16;
  const float cst = ws[OFF_CONST];

  // ---- stage A: both groups' P from one pass over W
  {
    const u16* W = side ? WB : WA;   // frag-ordered [17][2][64][8]
    const float* bias = ws + (side ? OFF_BB : OFF_BA);
    const int dd = (m15 & 3) + side * 4;
    short8 a0[2][2], a1[2][2];       // [grp][mt]
#pragma unroll
    for (int grp = 0; grp < 2; grp++) {
#pragma unroll
      for (int mt = 0; mt < 2; mt++) {
        const int e = mt * 4 + (m15 >> 2);
        const u16* ab = tok + ((size_t)(dd * 65536 + b0 + grp * 8 + e)) * 64 + quad * 8;
        a0[grp][mt] = *(const short8*)ab;
        a1[grp][mt] = *(const short8*)(ab + 32);
      }
    }
#pragma unroll
    for (int nt = 0; nt < 17; nt++) {
      const u16* bp = W + nt * 1024 + lane * 8;   // unit-stride 1KB/wave
      short8 bf0 = *(const short8*)bp;
      short8 bf1 = *(const short8*)(bp + 512);
      float bi = bias[nt * 16 + m15];
#pragma unroll
      for (int grp = 0; grp < 2; grp++) {
        u16* Pb = &P[grp][side * PSIDE];
#pragma unroll
        for (int mt = 0; mt < 2; mt++) {
          f32x4 acc = {0.f, 0.f, 0.f, 0.f};
          acc = __builtin_amdgcn_mfma_f32_16x16x32_bf16(a0[grp][mt], bf0, acc, 0, 0, 0);
          acc = __builtin_amdgcn_mfma_f32_16x16x32_bf16(a1[grp][mt], bf1, acc, 0, 0, 0);
#pragma unroll
          for (int r = 0; r < 4; r++)
            Pb[(mt * 16 + quad * 4 + r) * P_STRIDE + m15 + 16 * nt] =
                f2bf(acc[r] + bi);
        }
      }
    }
  }
  __syncthreads();
  // ---- stage B: both groups sequentially; elem = t>>4, sub = t&15 -> (h,q)
  const int elem = t >> 4, sub = t & 15;
  const int h = sub >> 2, q = sub & 3;
#pragma unroll
  for (int grp = 0; grp < 2; grp++) {
    const u16* Pg = &P[grp][0];
    float acc = 0.f;
#pragma unroll
    for (int tag = 0; tag < 4; tag++) {
      const int qs = tag & 1, cross = tag >> 1;
      const int ks2 = qs ^ cross;
      const u16* Pq = Pg + qs * PSIDE + (elem * 4 + q) * P_STRIDE + cross * 128 + h * 16;
      float qv[16];
      ld16(Pq, qv);
      const u16* Pk = Pg + ks2 * PSIDE + (elem * 4) * P_STRIDE + 64 + cross * 128 + h * 16;
      float sc[4];
#pragma unroll
      for (int k = 0; k < 4; k++) {
        float kv[16];
        ld16(Pk + k * P_STRIDE, kv);
        float s = 0.f;
#pragma unroll
        for (int i = 0; i < 16; i++) s += qv[i] * kv[i];
        sc[k] = s;
      }
      float mx = fmaxf(fmaxf(sc[0], sc[1]), fmaxf(sc[2], sc[3]));
      float e0 = __expf(sc[0] - mx), e1 = __expf(sc[1] - mx);
      float e2 = __expf(sc[2] - mx), e3 = __expf(sc[3] - mx);
      const u16* Psv = Pg + ks2 * PSIDE + (elem * 4) * P_STRIDE + 256 + cross * 4 + h;
      float o = e0 * bf2f(Psv[0]) + e1 * bf2f(Psv[P_STRIDE]) +
                e2 * bf2f(Psv[2 * P_STRIDE]) + e3 * bf2f(Psv[3 * P_STRIDE]);
      acc += o / (e0 + e1 + e2 + e3);
    }
    acc += __shfl_xor(acc, 1);
    acc += __shfl_xor(acc, 2);
    acc += __shfl_xor(acc, 4);
    acc += __shfl_xor(acc, 8);
    if (sub == 0) {
      float val = 0.125f * acc + cst;
      out[b0 + grp * 8 + elem] = val > 0.f ? val : 0.01f * val;
    }
  }
}

// ---------------------------------------------------------------- launch
extern "C" void kernel_launch(void* const* d_in, const int* in_sizes, int n_in,
                              void* d_out, int out_size, void* d_ws, size_t ws_size,
                              hipStream_t stream) {
  const float* x      = (const float*)d_in[0];
  const float* w1     = (const float*)d_in[1];
  const float* b1     = (const float*)d_in[2];
  const float* w2     = (const float*)d_in[3];
  const float* b2     = (const float*)d_in[4];
  const float* w3     = (const float*)d_in[5];
  const float* b3     = (const float*)d_in[6];
  const float* win_sa = (const float*)d_in[7];
  const float* bin_sa = (const float*)d_in[8];
  const float* wo_sa  = (const float*)d_in[9];
  const float* bo_sa  = (const float*)d_in[10];
  const float* win_sb = (const float*)d_in[11];
  const float* bin_sb = (const float*)d_in[12];
  const float* wo_sb  = (const float*)d_in[13];
  const float* bo_sb  = (const float*)d_in[14];
  const float* win_ca = (const float*)d_in[15];
  const float* bin_ca = (const float*)d_in[16];
  const float* wo_ca  = (const float*)d_in[17];
  const float* bo_ca  = (const float*)d_in[18];
  const float* win_cb = (const float*)d_in[19];
  const float* bin_cb = (const float*)d_in[20];
  const float* wo_cb  = (const float*)d_in[21];
  const float* bo_cb  = (const float*)d_in[22];
  const float* Wf     = (const float*)d_in[23];
  const float* bf     = (const float*)d_in[24];
  float* ws = (float*)d_ws;
  u16* WAp    = (u16*)((char*)d_ws + OFF_WA_B);
  u16* WBp    = (u16*)((char*)d_ws + OFF_WB_B);
  u16* w2p    = (u16*)((char*)d_ws + OFF_W2P_B);
  u16* w3p    = (u16*)((char*)d_ws + OFF_W3P_B);
  u16* tokbuf = (u16*)((char*)d_ws + OFF_TOK_B);
  float* out = (float*)d_out;

  prep_fold<<<4, 64, 0, stream>>>(win_sa, bin_sa, wo_sa, bo_sa,
                                  win_sb, bin_sb, wo_sb, bo_sb,
                                  win_ca, bin_ca, wo_ca, bo_ca,
                                  win_cb, bin_cb, wo_cb, bo_cb,
                                  Wf, ws);
  prep_pack<<<907, 256, 0, stream>>>(w2, w3, win_sa, win_sb, win_ca, win_cb,
                                     bin_sa, bin_sb, bin_ca, bin_cb, bf,
                                     ws, w2p, w3p, WAp, WBp);
  tokens_kernel<<<4096, 256, 0, stream>>>(x, w1, b1, b2, b3, w2p, w3p, tokbuf);
  attn_kernel<<<4096, 128, 0, stream>>>(ws, tokbuf, WAp, WBp, out);
}

// Round 17
// 232.970 us; speedup vs baseline: 1.1028x; 1.1028x over previous
//
#include <hip/hip_runtime.h>

typedef unsigned short u16;
typedef __attribute__((ext_vector_type(8))) short short8;
typedef __attribute__((ext_vector_type(4))) float f32x4;

// ws float-index offsets
#define OFF_U     0       // [4][4][64] folded value vectors (tag,h,k)
#define OFF_CV    1024    // [4][4]
#define OFF_CONST 1040
#define OFF_CTAG  1044    // [4] per-tag bo.wfh sums
#define OFF_BA    1056    // [272] fp32 bias for WA cols
#define OFF_BB    1328    // [272]
// ws byte offsets (16B-aligned)
#define OFF_WA_B    6400     // u16 [17][2][64][8]  WA frag-ordered
#define OFF_WB_B    41216    // u16 [17][2][64][8]  WB frag-ordered
#define OFF_W2P_B   76032    // u16 [8][32][64][8]  w2 in frag order
#define OFF_W3P_B   338176   // u16 [8][16][64][8]  w3 in frag order
#define OFF_TOK_B   469248   // u16 tokens, D-MAJOR: [8][65536][64]

#define P_STRIDE 280
#define PSIDE    (32 * P_STRIDE)

static __device__ __forceinline__ u16 f2bf(float f) {
  unsigned int bits = __float_as_uint(f);
  bits += 0x7fffu + ((bits >> 16) & 1u);
  return (u16)(bits >> 16);
}
static __device__ __forceinline__ float bf2f(u16 u) {
  return __uint_as_float(((unsigned int)u) << 16);
}
static __device__ __forceinline__ void ld16(const u16* p, float* o) {
  short8 v0 = *(const short8*)p;
  short8 v1 = *(const short8*)(p + 8);
#pragma unroll
  for (int i = 0; i < 8; i++) {
    o[i] = bf2f((u16)v0[i]);
    o[8 + i] = bf2f((u16)v1[i]);
  }
}

// ---------------------------------------------------------------- prep 1: fold
__global__ __launch_bounds__(64) void prep_fold(
    const float* __restrict__ win_sa, const float* __restrict__ bin_sa,
    const float* __restrict__ wo_sa,  const float* __restrict__ bo_sa,
    const float* __restrict__ win_sb, const float* __restrict__ bin_sb,
    const float* __restrict__ wo_sb,  const float* __restrict__ bo_sb,
    const float* __restrict__ win_ca, const float* __restrict__ bin_ca,
    const float* __restrict__ wo_ca,  const float* __restrict__ bo_ca,
    const float* __restrict__ win_cb, const float* __restrict__ bin_cb,
    const float* __restrict__ wo_cb,  const float* __restrict__ bo_cb,
    const float* __restrict__ Wf, float* __restrict__ ws) {
  __shared__ float v_lds[64];
  const int t = threadIdx.x;
  const int tag = blockIdx.x;
  const float* wins[4] = {win_sa, win_sb, win_ca, win_cb};
  const float* bins[4] = {bin_sa, bin_sb, bin_ca, bin_cb};
  const float* wos[4]  = {wo_sa, wo_sb, wo_ca, wo_cb};
  const float* bos[4]  = {bo_sa, bo_sb, bo_ca, bo_cb};
  const float* wfh = Wf + ((tag == 0 || tag == 2) ? 0 : 64);
  float v = 0.f;
#pragma unroll
  for (int e = 0; e < 64; e++) v += wos[tag][e * 64 + t] * wfh[e];
  v_lds[t] = v;
  __syncthreads();
#pragma unroll
  for (int h = 0; h < 4; h++) {
    float u = 0.f;
#pragma unroll
    for (int dp = 0; dp < 16; dp++)
      u += wins[tag][(128 + h * 16 + dp) * 64 + t] * v_lds[h * 16 + dp];
    ws[OFF_U + tag * 256 + h * 64 + t] = u;
  }
  if (t < 4) {
    float cv = 0.f;
#pragma unroll
    for (int dp = 0; dp < 16; dp++)
      cv += bins[tag][128 + t * 16 + dp] * v_lds[t * 16 + dp];
    ws[OFF_CV + tag * 4 + t] = cv;
  }
  if (t == 0) {
    float c = 0.f;
#pragma unroll
    for (int e = 0; e < 64; e++) c += bos[tag][e] * wfh[e];
    ws[OFF_CTAG + tag] = c;
  }
}

// ---------------------------------------------------------------- prep 2: pack
__global__ __launch_bounds__(256) void prep_pack(
    const float* __restrict__ w2, const float* __restrict__ w3,
    const float* __restrict__ win_sa, const float* __restrict__ win_sb,
    const float* __restrict__ win_ca, const float* __restrict__ win_cb,
    const float* __restrict__ bin_sa, const float* __restrict__ bin_sb,
    const float* __restrict__ bin_ca, const float* __restrict__ bin_cb,
    const float* __restrict__ bf,
    float* __restrict__ ws, u16* __restrict__ w2p, u16* __restrict__ w3p,
    u16* __restrict__ WA, u16* __restrict__ WB) {
  int idx = blockIdx.x * 256 + threadIdx.x;
  if (idx < 131072) {               // w2p[d][ks*8+nt][lane][j]
    int d = idx >> 14, rem = idx & 16383;
    int f = rem >> 9, ks = f >> 3, nt = f & 7;
    int r2 = rem & 511, l = r2 >> 3, j = r2 & 7;
    int quad = l >> 4, m15 = l & 15;
    w2p[idx] = f2bf(w2[(d * 128 + nt * 16 + m15) * 128 + ks * 32 + quad * 8 + j]);
  } else if (idx < 196608) {        // w3p[d][ks*4+nt][lane][j]
    int i = idx - 131072;
    int d = i >> 13, rem = i & 8191;
    int f = rem >> 9, ks = f >> 2, nt = f & 3;
    int r2 = rem & 511, l = r2 >> 3, j = r2 & 7;
    int quad = l >> 4, m15 = l & 15;
    w3p[i] = f2bf(w3[(d * 64 + nt * 16 + m15) * 128 + ks * 32 + quad * 8 + j]);
  } else if (idx < 214016) {        // WAf [17][2][64][8]
    int i = idx - 196608;
    int nt = i >> 10, rem = i & 1023;
    int half = rem >> 9, r2 = rem & 511, l = r2 >> 3, j = r2 & 7;
    int n = nt * 16 + (l & 15), k = half * 32 + (l >> 4) * 8 + j;
    float v;
    if (n < 64)       v = win_sa[n * 64 + k] * 0.25f;
    else if (n < 128) v = win_sa[n * 64 + k];
    else if (n < 192) v = win_ca[(n - 128) * 64 + k] * 0.25f;
    else if (n < 256) v = win_cb[(n - 128) * 64 + k];
    else if (n < 260) v = ws[OFF_U + 0 * 256 + (n - 256) * 64 + k];
    else if (n < 264) v = ws[OFF_U + 3 * 256 + (n - 260) * 64 + k];
    else              v = 0.f;
    WA[i] = f2bf(v);
  } else if (idx < 231424) {        // WBf [17][2][64][8]
    int i = idx - 214016;
    int nt = i >> 10, rem = i & 1023;
    int half = rem >> 9, r2 = rem & 511, l = r2 >> 3, j = r2 & 7;
    int n = nt * 16 + (l & 15), k = half * 32 + (l >> 4) * 8 + j;
    float v;
    if (n < 64)       v = win_sb[n * 64 + k] * 0.25f;
    else if (n < 128) v = win_sb[n * 64 + k];
    else if (n < 192) v = win_cb[(n - 128) * 64 + k] * 0.25f;
    else if (n < 256) v = win_ca[(n - 128) * 64 + k];
    else if (n < 260) v = ws[OFF_U + 1 * 256 + (n - 256) * 64 + k];
    else if (n < 264) v = ws[OFF_U + 2 * 256 + (n - 260) * 64 + k];
    else              v = 0.f;
    WB[i] = f2bf(v);
  } else if (idx < 231696) {        // bA
    int n = idx - 231424;
    float v;
    if (n < 64)       v = bin_sa[n] * 0.25f;
    else if (n < 128) v = bin_sa[n];
    else if (n < 192) v = bin_ca[n - 128] * 0.25f;
    else if (n < 256) v = bin_cb[n - 128];
    else if (n < 260) v = ws[OFF_CV + 0 * 4 + (n - 256)];
    else if (n < 264) v = ws[OFF_CV + 3 * 4 + (n - 260)];
    else              v = 0.f;
    ws[OFF_BA + n] = v;
  } else if (idx < 231968) {        // bB
    int n = idx - 231696;
    float v;
    if (n < 64)       v = bin_sb[n] * 0.25f;
    else if (n < 128) v = bin_sb[n];
    else if (n < 192) v = bin_cb[n - 128] * 0.25f;
    else if (n < 256) v = bin_ca[n - 128];
    else if (n < 260) v = ws[OFF_CV + 1 * 4 + (n - 256)];
    else if (n < 264) v = ws[OFF_CV + 2 * 4 + (n - 260)];
    else              v = 0.f;
    ws[OFF_BB + n] = v;
  } else if (idx == 231968) {
    ws[OFF_CONST] = 0.5f * (ws[OFF_CTAG] + ws[OFF_CTAG + 1] +
                            ws[OFF_CTAG + 2] + ws[OFF_CTAG + 3]) + bf[0];
  }
}

// ---------------------------------------------------------------- tokens (MFMA)
// R14 version (best total): ONE-SHOT, one 16-el tile per wave, block-level
// LDS weight staging, d-major contiguous stores.
__global__ __launch_bounds__(256, 2) void tokens_kernel(
    const float* __restrict__ x, const float* __restrict__ w1,
    const float* __restrict__ b1, const float* __restrict__ b2,
    const float* __restrict__ b3, const u16* __restrict__ w2p,
    const u16* __restrict__ w3p, u16* __restrict__ tok_out) {
  __shared__ __align__(16) u16 w2l[16384];
  __shared__ __align__(16) u16 w3l[8192];
  __shared__ __align__(16) u16 h2s[4][16 * 136];
  __shared__ __align__(16) u16 stg[4][16 * 72];
  const int t = threadIdx.x;
  const int wave = t >> 6, lane = t & 63;
  const int m15 = lane & 15, quad = lane >> 4;
  const int d = blockIdx.x & 7;
  const int g = blockIdx.x >> 3;
  const int b0 = g * 64 + wave * 16;
  const float xv = x[(size_t)(b0 + m15) * 8 + d];
#pragma unroll
  for (int c = 0; c < 8; c++)
    *(short8*)&w2l[c * 2048 + t * 8] = *(const short8*)&w2p[d * 16384 + c * 2048 + t * 8];
#pragma unroll
  for (int c = 0; c < 4; c++)
    *(short8*)&w3l[c * 2048 + t * 8] = *(const short8*)&w3p[d * 8192 + c * 2048 + t * 8];

  short8 afr[4];
#pragma unroll
  for (int ks = 0; ks < 4; ks++) {
    const float* w1p = w1 + d * 128 + ks * 32 + quad * 8;
    const float* b1p = b1 + d * 128 + ks * 32 + quad * 8;
    float4 wa = *(const float4*)w1p, wb = *(const float4*)(w1p + 4);
    float4 ba = *(const float4*)b1p, bb = *(const float4*)(b1p + 4);
    short8 a;
    a[0] = (short)f2bf(__sinf(xv * wa.x + ba.x));
    a[1] = (short)f2bf(__sinf(xv * wa.y + ba.y));
    a[2] = (short)f2bf(__sinf(xv * wa.z + ba.z));
    a[3] = (short)f2bf(__sinf(xv * wa.w + ba.w));
    a[4] = (short)f2bf(__sinf(xv * wb.x + bb.x));
    a[5] = (short)f2bf(__sinf(xv * wb.y + bb.y));
    a[6] = (short)f2bf(__sinf(xv * wb.z + bb.z));
    a[7] = (short)f2bf(__sinf(xv * wb.w + bb.w));
    afr[ks] = a;
  }
  __syncthreads();
  f32x4 acc2[8];
#pragma unroll
  for (int nt = 0; nt < 8; nt++) acc2[nt] = (f32x4){0.f, 0.f, 0.f, 0.f};
#pragma unroll
  for (int ks = 0; ks < 4; ks++) {
#pragma unroll
    for (int nt = 0; nt < 8; nt++) {
      short8 bfr = *(const short8*)&w2l[(ks * 8 + nt) * 512 + lane * 8];
      acc2[nt] = __builtin_amdgcn_mfma_f32_16x16x32_bf16(afr[ks], bfr, acc2[nt], 0, 0, 0);
    }
  }
#pragma unroll
  for (int nt = 0; nt < 8; nt++) {
    float bias = b2[d * 128 + m15 + 16 * nt];
#pragma unroll
    for (int r = 0; r < 4; r++)
      h2s[wave][(quad * 4 + r) * 136 + m15 + 16 * nt] =
          f2bf(__sinf(acc2[nt][r] + bias));
  }
  f32x4 acc3[4];
#pragma unroll
  for (int nt = 0; nt < 4; nt++) acc3[nt] = (f32x4){0.f, 0.f, 0.f, 0.f};
#pragma unroll
  for (int ks = 0; ks < 4; ks++) {
    short8 af = *(const short8*)(&h2s[wave][m15 * 136 + ks * 32 + quad * 8]);
#pragma unroll
    for (int nt = 0; nt < 4; nt++) {
      short8 bfr = *(const short8*)&w3l[(ks * 4 + nt) * 512 + lane * 8];
      acc3[nt] = __builtin_amdgcn_mfma_f32_16x16x32_bf16(af, bfr, acc3[nt], 0, 0, 0);
    }
  }
#pragma unroll
  for (int nt = 0; nt < 4; nt++) {
    float bias = b3[d * 64 + m15 + 16 * nt];
#pragma unroll
    for (int r = 0; r < 4; r++)
      stg[wave][(quad * 4 + r) * 72 + m15 + 16 * nt] = f2bf(acc3[nt][r] + bias);
  }
  {
    int chunk = lane & 7;
#pragma unroll
    for (int it = 0; it < 2; it++) {
      int row_l = (lane >> 3) + it * 8;
      short8 v = *(const short8*)&stg[wave][row_l * 72 + chunk * 8];
      *(short8*)(tok_out + ((size_t)(d * 65536 + b0 + row_l)) * 64 + chunk * 8) = v;
    }
  }
}

// ---------------------------------------------------------------- attention
// R14 version (best total): 128 thr, wave = side, 8 els, both-mt W reuse,
// frag-ordered W (unit-stride 1KB/wave loads), ld16 stage B, 35 KB LDS
// (4 blocks/CU).
__global__ __launch_bounds__(128, 4) void attn_kernel(
    const float* __restrict__ ws, const u16* __restrict__ tok,
    const u16* __restrict__ WA, const u16* __restrict__ WB,
    float* __restrict__ out) {
  __shared__ __align__(16) u16 P[2 * PSIDE];   // 35 KB
  const int t = threadIdx.x;
  const int wave = t >> 6, lane = t & 63;
  const int m15 = lane & 15, quad = lane >> 4;
  const int side = wave;
  const int b0 = blockIdx.x * 8;
  const float cst = ws[OFF_CONST];

  // ---- stage A: P[side] = tok @ W (+bias), both mt tiles per wave
  {
    const u16* W = side ? WB : WA;   // frag-ordered [17][2][64][8]
    const float* bias = ws + (side ? OFF_BB : OFF_BA);
    const int dd = (m15 & 3) + side * 4;
    short8 a0[2], a1[2];
#pragma unroll
    for (int mt = 0; mt < 2; mt++) {
      const int e = mt * 4 + (m15 >> 2);
      const u16* ab = tok + ((size_t)(dd * 65536 + b0 + e)) * 64 + quad * 8;
      a0[mt] = *(const short8*)ab;
      a1[mt] = *(const short8*)(ab + 32);
    }
    u16* Pb = &P[side * PSIDE];
#pragma unroll
    for (int nt = 0; nt < 17; nt++) {
      const u16* bp = W + nt * 1024 + lane * 8;   // unit-stride 1KB/wave
      short8 bf0 = *(const short8*)bp;
      short8 bf1 = *(const short8*)(bp + 512);
      float bi = bias[nt * 16 + m15];
#pragma unroll
      for (int mt = 0; mt < 2; mt++) {
        f32x4 acc = {0.f, 0.f, 0.f, 0.f};
        acc = __builtin_amdgcn_mfma_f32_16x16x32_bf16(a0[mt], bf0, acc, 0, 0, 0);
        acc = __builtin_amdgcn_mfma_f32_16x16x32_bf16(a1[mt], bf1, acc, 0, 0, 0);
#pragma unroll
        for (int r = 0; r < 4; r++)
          Pb[(mt * 16 + quad * 4 + r) * P_STRIDE + m15 + 16 * nt] =
              f2bf(acc[r] + bi);
      }
    }
  }
  __syncthreads();
  // ---- stage B: elem = t>>4 (8 els), sub = t&15 -> (h, q), all 4 tags
  const int elem = t >> 4, sub = t & 15;
  const int h = sub >> 2, q = sub & 3;
  float acc = 0.f;
#pragma unroll
  for (int tag = 0; tag < 4; tag++) {
    const int qs = tag & 1, cross = tag >> 1;
    const int ks2 = qs ^ cross;
    const u16* Pq = P + qs * PSIDE + (elem * 4 + q) * P_STRIDE + cross * 128 + h * 16;
    float qv[16];
    ld16(Pq, qv);
    const u16* Pk = P + ks2 * PSIDE + (elem * 4) * P_STRIDE + 64 + cross * 128 + h * 16;
    float sc[4];
#pragma unroll
    for (int k = 0; k < 4; k++) {
      float kv[16];
      ld16(Pk + k * P_STRIDE, kv);
      float s = 0.f;
#pragma unroll
      for (int i = 0; i < 16; i++) s += qv[i] * kv[i];
      sc[k] = s;
    }
    float mx = fmaxf(fmaxf(sc[0], sc[1]), fmaxf(sc[2], sc[3]));
    float e0 = __expf(sc[0] - mx), e1 = __expf(sc[1] - mx);
    float e2 = __expf(sc[2] - mx), e3 = __expf(sc[3] - mx);
    const u16* Psv = P + ks2 * PSIDE + (elem * 4) * P_STRIDE + 256 + cross * 4 + h;
    float o = e0 * bf2f(Psv[0]) + e1 * bf2f(Psv[P_STRIDE]) +
              e2 * bf2f(Psv[2 * P_STRIDE]) + e3 * bf2f(Psv[3 * P_STRIDE]);
    acc += o / (e0 + e1 + e2 + e3);
  }
  acc += __shfl_xor(acc, 1);
  acc += __shfl_xor(acc, 2);
  acc += __shfl_xor(acc, 4);
  acc += __shfl_xor(acc, 8);
  if (sub == 0) {
    float val = 0.125f * acc + cst;
    out[b0 + elem] = val > 0.f ? val : 0.01f * val;
  }
}

// ---------------------------------------------------------------- launch
extern "C" void kernel_launch(void* const* d_in, const int* in_sizes, int n_in,
                              void* d_out, int out_size, void* d_ws, size_t ws_size,
                              hipStream_t stream) {
  const float* x      = (const float*)d_in[0];
  const float* w1     = (const float*)d_in[1];
  const float* b1     = (const float*)d_in[2];
  const float* w2     = (const float*)d_in[3];
  const float* b2     = (const float*)d_in[4];
  const float* w3     = (const float*)d_in[5];
  const float* b3     = (const float*)d_in[6];
  const float* win_sa = (const float*)d_in[7];
  const float* bin_sa = (const float*)d_in[8];
  const float* wo_sa  = (const float*)d_in[9];
  const float* bo_sa  = (const float*)d_in[10];
  const float* win_sb = (const float*)d_in[11];
  const float* bin_sb = (const float*)d_in[12];
  const float* wo_sb  = (const float*)d_in[13];
  const float* bo_sb  = (const float*)d_in[14];
  const float* win_ca = (const float*)d_in[15];
  const float* bin_ca = (const float*)d_in[16];
  const float* wo_ca  = (const float*)d_in[17];
  const float* bo_ca  = (const float*)d_in[18];
  const float* win_cb = (const float*)d_in[19];
  const float* bin_cb = (const float*)d_in[20];
  const float* wo_cb  = (const float*)d_in[21];
  const float* bo_cb  = (const float*)d_in[22];
  const float* Wf     = (const float*)d_in[23];
  const float* bf     = (const float*)d_in[24];
  float* ws = (float*)d_ws;
  u16* WAp    = (u16*)((char*)d_ws + OFF_WA_B);
  u16* WBp    = (u16*)((char*)d_ws + OFF_WB_B);
  u16* w2p    = (u16*)((char*)d_ws + OFF_W2P_B);
  u16* w3p    = (u16*)((char*)d_ws + OFF_W3P_B);
  u16* tokbuf = (u16*)((char*)d_ws + OFF_TOK_B);
  float* out = (float*)d_out;

  prep_fold<<<4, 64, 0, stream>>>(win_sa, bin_sa, wo_sa, bo_sa,
                                  win_sb, bin_sb, wo_sb, bo_sb,
                                  win_ca, bin_ca, wo_ca, bo_ca,
                                  win_cb, bin_cb, wo_cb, bo_cb,
                                  Wf, ws);
  prep_pack<<<907, 256, 0, stream>>>(w2, w3, win_sa, win_sb, win_ca, win_cb,
                                     bin_sa, bin_sb, bin_ca, bin_cb, bf,
                                     ws, w2p, w3p, WAp, WBp);
  tokens_kernel<<<8192, 256, 0, stream>>>(x, w1, b1, b2, b3, w2p, w3p, tokbuf);
  attn_kernel<<<8192, 128, 0, stream>>>(ws, tokbuf, WAp, WBp, out);
}

// Round 18
// 225.776 us; speedup vs baseline: 1.1380x; 1.0319x over previous
//
#include <hip/hip_runtime.h>

typedef unsigned short u16;
typedef __attribute__((ext_vector_type(8))) short short8;
typedef __attribute__((ext_vector_type(4))) float f32x4;

// ws float-index offsets
#define OFF_U     0       // [4][4][64] folded value vectors (tag,h,k)
#define OFF_CV    1024    // [4][4]
#define OFF_CONST 1040
#define OFF_CTAG  1044    // [4] per-tag bo.wfh sums
#define OFF_BA    1056    // [272] fp32 bias for WA cols
#define OFF_BB    1328    // [272]
// ws byte offsets (16B-aligned)
#define OFF_WA_B    6400     // u16 [17][2][64][8]  WA frag-ordered
#define OFF_WB_B    41216    // u16 [17][2][64][8]  WB frag-ordered
#define OFF_W2P_B   76032    // u16 [8][32][64][8]  w2 in frag order
#define OFF_W3P_B   338176   // u16 [8][16][64][8]  w3 in frag order
#define OFF_TOK_B   469248   // u16 tokens, D-MAJOR: [8][65536][64]

#define P_STRIDE 280
#define PSIDE    (32 * P_STRIDE)

static __device__ __forceinline__ u16 f2bf(float f) {
  unsigned int bits = __float_as_uint(f);
  bits += 0x7fffu + ((bits >> 16) & 1u);
  return (u16)(bits >> 16);
}
static __device__ __forceinline__ float bf2f(u16 u) {
  return __uint_as_float(((unsigned int)u) << 16);
}
static __device__ __forceinline__ void ld16(const u16* p, float* o) {
  short8 v0 = *(const short8*)p;
  short8 v1 = *(const short8*)(p + 8);
#pragma unroll
  for (int i = 0; i < 8; i++) {
    o[i] = bf2f((u16)v0[i]);
    o[8 + i] = bf2f((u16)v1[i]);
  }
}

// ---------------------------------------------------------------- prep 1: fold
__global__ __launch_bounds__(64) void prep_fold(
    const float* __restrict__ win_sa, const float* __restrict__ bin_sa,
    const float* __restrict__ wo_sa,  const float* __restrict__ bo_sa,
    const float* __restrict__ win_sb, const float* __restrict__ bin_sb,
    const float* __restrict__ wo_sb,  const float* __restrict__ bo_sb,
    const float* __restrict__ win_ca, const float* __restrict__ bin_ca,
    const float* __restrict__ wo_ca,  const float* __restrict__ bo_ca,
    const float* __restrict__ win_cb, const float* __restrict__ bin_cb,
    const float* __restrict__ wo_cb,  const float* __restrict__ bo_cb,
    const float* __restrict__ Wf, float* __restrict__ ws) {
  __shared__ float v_lds[64];
  const int t = threadIdx.x;
  const int tag = blockIdx.x;
  const float* wins[4] = {win_sa, win_sb, win_ca, win_cb};
  const float* bins[4] = {bin_sa, bin_sb, bin_ca, bin_cb};
  const float* wos[4]  = {wo_sa, wo_sb, wo_ca, wo_cb};
  const float* bos[4]  = {bo_sa, bo_sb, bo_ca, bo_cb};
  const float* wfh = Wf + ((tag == 0 || tag == 2) ? 0 : 64);
  float v = 0.f;
#pragma unroll
  for (int e = 0; e < 64; e++) v += wos[tag][e * 64 + t] * wfh[e];
  v_lds[t] = v;
  __syncthreads();
#pragma unroll
  for (int h = 0; h < 4; h++) {
    float u = 0.f;
#pragma unroll
    for (int dp = 0; dp < 16; dp++)
      u += wins[tag][(128 + h * 16 + dp) * 64 + t] * v_lds[h * 16 + dp];
    ws[OFF_U + tag * 256 + h * 64 + t] = u;
  }
  if (t < 4) {
    float cv = 0.f;
#pragma unroll
    for (int dp = 0; dp < 16; dp++)
      cv += bins[tag][128 + t * 16 + dp] * v_lds[t * 16 + dp];
    ws[OFF_CV + tag * 4 + t] = cv;
  }
  if (t == 0) {
    float c = 0.f;
#pragma unroll
    for (int e = 0; e < 64; e++) c += bos[tag][e] * wfh[e];
    ws[OFF_CTAG + tag] = c;
  }
}

// ---------------------------------------------------------------- prep 2: pack
__global__ __launch_bounds__(256) void prep_pack(
    const float* __restrict__ w2, const float* __restrict__ w3,
    const float* __restrict__ win_sa, const float* __restrict__ win_sb,
    const float* __restrict__ win_ca, const float* __restrict__ win_cb,
    const float* __restrict__ bin_sa, const float* __restrict__ bin_sb,
    const float* __restrict__ bin_ca, const float* __restrict__ bin_cb,
    const float* __restrict__ bf,
    float* __restrict__ ws, u16* __restrict__ w2p, u16* __restrict__ w3p,
    u16* __restrict__ WA, u16* __restrict__ WB) {
  int idx = blockIdx.x * 256 + threadIdx.x;
  if (idx < 131072) {               // w2p[d][ks*8+nt][lane][j]
    int d = idx >> 14, rem = idx & 16383;
    int f = rem >> 9, ks = f >> 3, nt = f & 7;
    int r2 = rem & 511, l = r2 >> 3, j = r2 & 7;
    int quad = l >> 4, m15 = l & 15;
    w2p[idx] = f2bf(w2[(d * 128 + nt * 16 + m15) * 128 + ks * 32 + quad * 8 + j]);
  } else if (idx < 196608) {        // w3p[d][ks*4+nt][lane][j]
    int i = idx - 131072;
    int d = i >> 13, rem = i & 8191;
    int f = rem >> 9, ks = f >> 2, nt = f & 3;
    int r2 = rem & 511, l = r2 >> 3, j = r2 & 7;
    int quad = l >> 4, m15 = l & 15;
    w3p[i] = f2bf(w3[(d * 64 + nt * 16 + m15) * 128 + ks * 32 + quad * 8 + j]);
  } else if (idx < 214016) {        // WAf [17][2][64][8]
    int i = idx - 196608;
    int nt = i >> 10, rem = i & 1023;
    int half = rem >> 9, r2 = rem & 511, l = r2 >> 3, j = r2 & 7;
    int n = nt * 16 + (l & 15), k = half * 32 + (l >> 4) * 8 + j;
    float v;
    if (n < 64)       v = win_sa[n * 64 + k] * 0.25f;
    else if (n < 128) v = win_sa[n * 64 + k];
    else if (n < 192) v = win_ca[(n - 128) * 64 + k] * 0.25f;
    else if (n < 256) v = win_cb[(n - 128) * 64 + k];
    else if (n < 260) v = ws[OFF_U + 0 * 256 + (n - 256) * 64 + k];
    else if (n < 264) v = ws[OFF_U + 3 * 256 + (n - 260) * 64 + k];
    else              v = 0.f;
    WA[i] = f2bf(v);
  } else if (idx < 231424) {        // WBf [17][2][64][8]
    int i = idx - 214016;
    int nt = i >> 10, rem = i & 1023;
    int half = rem >> 9, r2 = rem & 511, l = r2 >> 3, j = r2 & 7;
    int n = nt * 16 + (l & 15), k = half * 32 + (l >> 4) * 8 + j;
    float v;
    if (n < 64)       v = win_sb[n * 64 + k] * 0.25f;
    else if (n < 128) v = win_sb[n * 64 + k];
    else if (n < 192) v = win_cb[(n - 128) * 64 + k] * 0.25f;
    else if (n < 256) v = win_ca[(n - 128) * 64 + k];
    else if (n < 260) v = ws[OFF_U + 1 * 256 + (n - 256) * 64 + k];
    else if (n < 264) v = ws[OFF_U + 2 * 256 + (n - 260) * 64 + k];
    else              v = 0.f;
    WB[i] = f2bf(v);
  } else if (idx < 231696) {        // bA
    int n = idx - 231424;
    float v;
    if (n < 64)       v = bin_sa[n] * 0.25f;
    else if (n < 128) v = bin_sa[n];
    else if (n < 192) v = bin_ca[n - 128] * 0.25f;
    else if (n < 256) v = bin_cb[n - 128];
    else if (n < 260) v = ws[OFF_CV + 0 * 4 + (n - 256)];
    else if (n < 264) v = ws[OFF_CV + 3 * 4 + (n - 260)];
    else              v = 0.f;
    ws[OFF_BA + n] = v;
  } else if (idx < 231968) {        // bB
    int n = idx - 231696;
    float v;
    if (n < 64)       v = bin_sb[n] * 0.25f;
    else if (n < 128) v = bin_sb[n];
    else if (n < 192) v = bin_cb[n - 128] * 0.25f;
    else if (n < 256) v = bin_ca[n - 128];
    else if (n < 260) v = ws[OFF_CV + 1 * 4 + (n - 256)];
    else if (n < 264) v = ws[OFF_CV + 2 * 4 + (n - 260)];
    else              v = 0.f;
    ws[OFF_BB + n] = v;
  } else if (idx == 231968) {
    ws[OFF_CONST] = 0.5f * (ws[OFF_CTAG] + ws[OFF_CTAG + 1] +
                            ws[OFF_CTAG + 2] + ws[OFF_CTAG + 3]) + bf[0];
  }
}

// ---------------------------------------------------------------- tokens (MFMA)
// R14 + LDS diet: w3 streamed from L2 (frag-ordered, unit-stride/wave) and
// h2s/stg unioned (same-wave LDS ops are program-ordered). LDS 75.8 -> 49.4
// KB => 3 blocks/CU (12 waves, +50% over R14's 8) on a latency-bound kernel.
__global__ __launch_bounds__(256, 3) void tokens_kernel(
    const float* __restrict__ x, const float* __restrict__ w1,
    const float* __restrict__ b1, const float* __restrict__ b2,
    const float* __restrict__ b3, const u16* __restrict__ w2p,
    const u16* __restrict__ w3p, u16* __restrict__ tok_out) {
  __shared__ __align__(16) u16 w2l[16384];
  __shared__ __align__(16) u16 scratch[4][16 * 136];   // h2s, then store-stage
  const int t = threadIdx.x;
  const int wave = t >> 6, lane = t & 63;
  const int m15 = lane & 15, quad = lane >> 4;
  const int d = blockIdx.x & 7;
  const int g = blockIdx.x >> 3;
  const int b0 = g * 64 + wave * 16;
  const float xv = x[(size_t)(b0 + m15) * 8 + d];
  // ---- stage w2 to LDS (lane-linear, coalesced; L2-hot per XCD)
#pragma unroll
  for (int c = 0; c < 8; c++)
    *(short8*)&w2l[c * 2048 + t * 8] = *(const short8*)&w2p[d * 16384 + c * 2048 + t * 8];

  // ---- h1 -> A-frags (A[m=lane&15][k=quad*8+j]); w1/b1 L1-resident
  short8 afr[4];
#pragma unroll
  for (int ks = 0; ks < 4; ks++) {
    const float* w1p = w1 + d * 128 + ks * 32 + quad * 8;
    const float* b1p = b1 + d * 128 + ks * 32 + quad * 8;
    float4 wa = *(const float4*)w1p, wb = *(const float4*)(w1p + 4);
    float4 ba = *(const float4*)b1p, bb = *(const float4*)(b1p + 4);
    short8 a;
    a[0] = (short)f2bf(__sinf(xv * wa.x + ba.x));
    a[1] = (short)f2bf(__sinf(xv * wa.y + ba.y));
    a[2] = (short)f2bf(__sinf(xv * wa.z + ba.z));
    a[3] = (short)f2bf(__sinf(xv * wa.w + ba.w));
    a[4] = (short)f2bf(__sinf(xv * wb.x + bb.x));
    a[5] = (short)f2bf(__sinf(xv * wb.y + bb.y));
    a[6] = (short)f2bf(__sinf(xv * wb.z + bb.z));
    a[7] = (short)f2bf(__sinf(xv * wb.w + bb.w));
    afr[ks] = a;
  }
  __syncthreads();
  // ---- layer2 MFMA: B-frags via conflict-free ds_read_b128
  f32x4 acc2[8];
#pragma unroll
  for (int nt = 0; nt < 8; nt++) acc2[nt] = (f32x4){0.f, 0.f, 0.f, 0.f};
#pragma unroll
  for (int ks = 0; ks < 4; ks++) {
#pragma unroll
    for (int nt = 0; nt < 8; nt++) {
      short8 bfr = *(const short8*)&w2l[(ks * 8 + nt) * 512 + lane * 8];
      acc2[nt] = __builtin_amdgcn_mfma_f32_16x16x32_bf16(afr[ks], bfr, acc2[nt], 0, 0, 0);
    }
  }
  // ---- ep2 -> wave-private scratch (C layout: col=m15, row=quad*4+r)
#pragma unroll
  for (int nt = 0; nt < 8; nt++) {
    float bias = b2[d * 128 + m15 + 16 * nt];
#pragma unroll
    for (int r = 0; r < 4; r++)
      scratch[wave][(quad * 4 + r) * 136 + m15 + 16 * nt] =
          f2bf(__sinf(acc2[nt][r] + bias));
  }
  // ---- layer3 MFMA: A from LDS, B streamed from L2 (frag-ordered w3p)
  const u16* w3base = w3p + d * 8192 + lane * 8;
  f32x4 acc3[4];
#pragma unroll
  for (int nt = 0; nt < 4; nt++) acc3[nt] = (f32x4){0.f, 0.f, 0.f, 0.f};
#pragma unroll
  for (int ks = 0; ks < 4; ks++) {
    short8 af = *(const short8*)(&scratch[wave][m15 * 136 + ks * 32 + quad * 8]);
#pragma unroll
    for (int nt = 0; nt < 4; nt++) {
      short8 bfr = *(const short8*)(w3base + (ks * 4 + nt) * 512);
      acc3[nt] = __builtin_amdgcn_mfma_f32_16x16x32_bf16(af, bfr, acc3[nt], 0, 0, 0);
    }
  }
  // ---- ep3: re-stage into scratch (same-wave order-safe), contiguous stores
#pragma unroll
  for (int nt = 0; nt < 4; nt++) {
    float bias = b3[d * 64 + m15 + 16 * nt];
#pragma unroll
    for (int r = 0; r < 4; r++)
      scratch[wave][(quad * 4 + r) * 136 + m15 + 16 * nt] = f2bf(acc3[nt][r] + bias);
  }
  {
    int chunk = lane & 7;
#pragma unroll
    for (int it = 0; it < 2; it++) {
      int row_l = (lane >> 3) + it * 8;
      short8 v = *(const short8*)&scratch[wave][row_l * 136 + chunk * 8];
      *(short8*)(tok_out + ((size_t)(d * 65536 + b0 + row_l)) * 64 + chunk * 8) = v;
    }
  }
}

// ---------------------------------------------------------------- attention
// R14 version (frozen): 128 thr, wave = side, 8 els, both-mt W reuse,
// frag-ordered W (unit-stride 1KB/wave loads), ld16 stage B, 35 KB LDS.
__global__ __launch_bounds__(128, 4) void attn_kernel(
    const float* __restrict__ ws, const u16* __restrict__ tok,
    const u16* __restrict__ WA, const u16* __restrict__ WB,
    float* __restrict__ out) {
  __shared__ __align__(16) u16 P[2 * PSIDE];   // 35 KB
  const int t = threadIdx.x;
  const int wave = t >> 6, lane = t & 63;
  const int m15 = lane & 15, quad = lane >> 4;
  const int side = wave;
  const int b0 = blockIdx.x * 8;
  const float cst = ws[OFF_CONST];

  // ---- stage A: P[side] = tok @ W (+bias), both mt tiles per wave
  {
    const u16* W = side ? WB : WA;   // frag-ordered [17][2][64][8]
    const float* bias = ws + (side ? OFF_BB : OFF_BA);
    const int dd = (m15 & 3) + side * 4;
    short8 a0[2], a1[2];
#pragma unroll
    for (int mt = 0; mt < 2; mt++) {
      const int e = mt * 4 + (m15 >> 2);
      const u16* ab = tok + ((size_t)(dd * 65536 + b0 + e)) * 64 + quad * 8;
      a0[mt] = *(const short8*)ab;
      a1[mt] = *(const short8*)(ab + 32);
    }
    u16* Pb = &P[side * PSIDE];
#pragma unroll
    for (int nt = 0; nt < 17; nt++) {
      const u16* bp = W + nt * 1024 + lane * 8;   // unit-stride 1KB/wave
      short8 bf0 = *(const short8*)bp;
      short8 bf1 = *(const short8*)(bp + 512);
      float bi = bias[nt * 16 + m15];
#pragma unroll
      for (int mt = 0; mt < 2; mt++) {
        f32x4 acc = {0.f, 0.f, 0.f, 0.f};
        acc = __builtin_amdgcn_mfma_f32_16x16x32_bf16(a0[mt], bf0, acc, 0, 0, 0);
        acc = __builtin_amdgcn_mfma_f32_16x16x32_bf16(a1[mt], bf1, acc, 0, 0, 0);
#pragma unroll
        for (int r = 0; r < 4; r++)
          Pb[(mt * 16 + quad * 4 + r) * P_STRIDE + m15 + 16 * nt] =
              f2bf(acc[r] + bi);
      }
    }
  }
  __syncthreads();
  // ---- stage B: elem = t>>4 (8 els), sub = t&15 -> (h, q), all 4 tags
  const int elem = t >> 4, sub = t & 15;
  const int h = sub >> 2, q = sub & 3;
  float acc = 0.f;
#pragma unroll
  for (int tag = 0; tag < 4; tag++) {
    const int qs = tag & 1, cross = tag >> 1;
    const int ks2 = qs ^ cross;
    const u16* Pq = P + qs * PSIDE + (elem * 4 + q) * P_STRIDE + cross * 128 + h * 16;
    float qv[16];
    ld16(Pq, qv);
    const u16* Pk = P + ks2 * PSIDE + (elem * 4) * P_STRIDE + 64 + cross * 128 + h * 16;
    float sc[4];
#pragma unroll
    for (int k = 0; k < 4; k++) {
      float kv[16];
      ld16(Pk + k * P_STRIDE, kv);
      float s = 0.f;
#pragma unroll
      for (int i = 0; i < 16; i++) s += qv[i] * kv[i];
      sc[k] = s;
    }
    float mx = fmaxf(fmaxf(sc[0], sc[1]), fmaxf(sc[2], sc[3]));
    float e0 = __expf(sc[0] - mx), e1 = __expf(sc[1] - mx);
    float e2 = __expf(sc[2] - mx), e3 = __expf(sc[3] - mx);
    const u16* Psv = P + ks2 * PSIDE + (elem * 4) * P_STRIDE + 256 + cross * 4 + h;
    float o = e0 * bf2f(Psv[0]) + e1 * bf2f(Psv[P_STRIDE]) +
              e2 * bf2f(Psv[2 * P_STRIDE]) + e3 * bf2f(Psv[3 * P_STRIDE]);
    acc += o / (e0 + e1 + e2 + e3);
  }
  acc += __shfl_xor(acc, 1);
  acc += __shfl_xor(acc, 2);
  acc += __shfl_xor(acc, 4);
  acc += __shfl_xor(acc, 8);
  if (sub == 0) {
    float val = 0.125f * acc + cst;
    out[b0 + elem] = val > 0.f ? val : 0.01f * val;
  }
}

// ---------------------------------------------------------------- launch
extern "C" void kernel_launch(void* const* d_in, const int* in_sizes, int n_in,
                              void* d_out, int out_size, void* d_ws, size_t ws_size,
                              hipStream_t stream) {
  const float* x      = (const float*)d_in[0];
  const float* w1     = (const float*)d_in[1];
  const float* b1     = (const float*)d_in[2];
  const float* w2     = (const float*)d_in[3];
  const float* b2     = (const float*)d_in[4];
  const float* w3     = (const float*)d_in[5];
  const float* b3     = (const float*)d_in[6];
  const float* win_sa = (const float*)d_in[7];
  const float* bin_sa = (const float*)d_in[8];
  const float* wo_sa  = (const float*)d_in[9];
  const float* bo_sa  = (const float*)d_in[10];
  const float* win_sb = (const float*)d_in[11];
  const float* bin_sb = (const float*)d_in[12];
  const float* wo_sb  = (const float*)d_in[13];
  const float* bo_sb  = (const float*)d_in[14];
  const float* win_ca = (const float*)d_in[15];
  const float* bin_ca = (const float*)d_in[16];
  const float* wo_ca  = (const float*)d_in[17];
  const float* bo_ca  = (const float*)d_in[18];
  const float* win_cb = (const float*)d_in[19];
  const float* bin_cb = (const float*)d_in[20];
  const float* wo_cb  = (const float*)d_in[21];
  const float* bo_cb  = (const float*)d_in[22];
  const float* Wf     = (const float*)d_in[23];
  const float* bf     = (const float*)d_in[24];
  float* ws = (float*)d_ws;
  u16* WAp    = (u16*)((char*)d_ws + OFF_WA_B);
  u16* WBp    = (u16*)((char*)d_ws + OFF_WB_B);
  u16* w2p    = (u16*)((char*)d_ws + OFF_W2P_B);
  u16* w3p    = (u16*)((char*)d_ws + OFF_W3P_B);
  u16* tokbuf = (u16*)((char*)d_ws + OFF_TOK_B);
  float* out = (float*)d_out;

  prep_fold<<<4, 64, 0, stream>>>(win_sa, bin_sa, wo_sa, bo_sa,
                                  win_sb, bin_sb, wo_sb, bo_sb,
                                  win_ca, bin_ca, wo_ca, bo_ca,
                                  win_cb, bin_cb, wo_cb, bo_cb,
                                  Wf, ws);
  prep_pack<<<907, 256, 0, stream>>>(w2, w3, win_sa, win_sb, win_ca, win_cb,
                                     bin_sa, bin_sb, bin_ca, bin_cb, bf,
                                     ws, w2p, w3p, WAp, WBp);
  tokens_kernel<<<8192, 256, 0, stream>>>(x, w1, b1, b2, b3, w2p, w3p, tokbuf);
  attn_kernel<<<8192, 128, 0, stream>>>(ws, tokbuf, WAp, WBp, out);
}